// Round 4
// baseline (891.260 us; speedup 1.0000x reference)
//
#include <hip/hip_runtime.h>

// EfficientAttention MI355X — round 7:
//  * k_fused: revert to round-5 interleaved 72-FMA body (round-6 sweep split
//    regressed 365->421). Add explicit ping-pong double-buffer of x chunks
//    (prefetch chunk c+1 while consuming c; prefetch next tile's chunk 0
//    during the last consume). Channel order unchanged -> bit-identical.
//  * k_combine: 2 -> 72 blocks (thread per (n,kg,o) output, 24 FMAs).
//  * k_out: float4 qsm layout kept; explicit 1-deep prefetch, peeled tail.

#define NV 131072
#define CC 96
#define NB 2
#define HK 24
#define PAD 68
#define BPN 384          // k_fused blocks per batch index
#define TILES_N 2048     // 64-position tiles per batch index

// ---------------------------------------------------------------- kernel 0
__global__ __launch_bounds__(256) void k_prep(
    const float* __restrict__ Wq, const float* __restrict__ Wk,
    const float* __restrict__ Wv,
    float* __restrict__ Wqt, float* __restrict__ Wkt, float* __restrict__ Wvt)
{
    const int i = blockIdx.x * 256 + threadIdx.x;
    if (i >= CC * CC) return;
    const int h = i / (HK * CC);
    const int r = i % (HK * CC);
    const int c = r / HK;
    const int j = r % HK;
    const int src = (h * HK + j) * CC + c;
    Wqt[i] = Wq[src];
    Wkt[i] = Wk[src];
    Wvt[i] = Wv[src];
}

// ---------------------------------------------------------------- kernel 1
__global__ __launch_bounds__(256, 3) void k_fused(
    const float* __restrict__ x,
    const float* __restrict__ Wqt, const float* __restrict__ bq,
    const float* __restrict__ Wkt, const float* __restrict__ bk,
    const float* __restrict__ Wvt, const float* __restrict__ bv,
    float* __restrict__ qsm, float* __restrict__ ctx, float* __restrict__ ksum)
{
    __shared__ float eks[4 * HK * PAD];   // per-wave exp(k) tiles [24][68]
    __shared__ float vls[4 * HK * PAD];   // per-wave v tiles      [24][68]
    const int tid = threadIdx.x;
    const int pl  = tid & 63;
    const int gu  = __builtin_amdgcn_readfirstlane(tid >> 6);  // wave = head
    const int n   = blockIdx.x / BPN;
    const int r0  = blockIdx.x % BPN;
    const int a   = pl >> 3, b = pl & 7;  // 8x8 lane grid for 3x3 ctx tile

    float* __restrict__ ek = eks + gu * HK * PAD;
    float* __restrict__ vl = vls + gu * HK * PAD;
    const float* __restrict__ Wqh = Wqt + gu * HK * CC;  // [c][j] contiguous
    const float* __restrict__ Wkh = Wkt + gu * HK * CC;
    const float* __restrict__ Wvh = Wvt + gu * HK * CC;

    float cacc[9];
#pragma unroll
    for (int k = 0; k < 9; ++k) cacc[k] = 0.f;
    float ksacc = 0.f;

    float aq[HK], ak[HK], av[HK];
    float xra[16], xrb[16];

    // interleaved 72-accumulator consume of one 16-channel chunk
    auto CONS = [&](const float (&xr)[16], int cb) {
#pragma unroll
        for (int u = 0; u < 16; ++u) {
            const int c = cb + u;
            const float xv = xr[u];
#pragma unroll
            for (int j = 0; j < HK; ++j) {
                aq[j] = fmaf(Wqh[c * HK + j], xv, aq[j]);
                ak[j] = fmaf(Wkh[c * HK + j], xv, ak[j]);
                av[j] = fmaf(Wvh[c * HK + j], xv, av[j]);
            }
        }
    };
    auto LD = [&](float (&xr)[16], size_t base, int cb) {
#pragma unroll
        for (int u = 0; u < 16; ++u)
            xr[u] = x[base + (size_t)(cb + u) * NV];
    };

    // prologue: chunk 0 of first tile
    size_t xb = (size_t)n * CC * NV + (size_t)r0 * 64 + pl;
    LD(xra, xb, 0);

    for (int tt = r0; tt < TILES_N; tt += BPN) {
        const size_t xnext = (size_t)n * CC * NV + (size_t)(tt + BPN) * 64 + pl;

#pragma unroll
        for (int j = 0; j < HK; ++j) {
            aq[j] = bq[gu * HK + j];
            ak[j] = bk[gu * HK + j];
            av[j] = bv[gu * HK + j];
        }

        // ping-pong: prefetch next chunk while consuming current
        LD(xrb, xb, 16);  CONS(xra, 0);
        LD(xra, xb, 32);  CONS(xrb, 16);
        LD(xrb, xb, 48);  CONS(xra, 32);
        LD(xra, xb, 64);  CONS(xrb, 48);
        LD(xrb, xb, 80);  CONS(xra, 64);
        if (tt + BPN < TILES_N) LD(xra, xnext, 0);   // next tile's chunk 0
        CONS(xrb, 80);
        xb = xnext;

        // ---- q softmax (registers) -> qsm (float4 q-group layout)
        {
            float mx = aq[0];
#pragma unroll
            for (int j = 1; j < HK; ++j) mx = fmaxf(mx, aq[j]);
            float s = 0.f;
#pragma unroll
            for (int j = 0; j < HK; ++j) { aq[j] = __expf(aq[j] - mx); s += aq[j]; }
            const float inv = 1.f / s;
            float4* __restrict__ qs4 = (float4*)qsm;
            const size_t qb4 = ((size_t)n * 24 + gu * 6) * NV + (size_t)tt * 64 + pl;
#pragma unroll
            for (int jj = 0; jj < 6; ++jj) {
                float4 t;
                t.x = aq[4 * jj + 0] * inv;
                t.y = aq[4 * jj + 1] * inv;
                t.z = aq[4 * jj + 2] * inv;
                t.w = aq[4 * jj + 3] * inv;
                qs4[qb4 + (size_t)jj * NV] = t;
            }
        }

        // ---- exp(k) and v into this wave's private LDS (no barrier needed)
#pragma unroll
        for (int j = 0; j < HK; ++j) ek[j * PAD + pl] = __expf(ak[j]);
#pragma unroll
        for (int j = 0; j < HK; ++j) vl[j * PAD + pl] = av[j];

        // ---- ksum: lane < 24 sums its exp(k) row
        if (pl < HK) {
            const float4* __restrict__ rp = (const float4*)(ek + pl * PAD);
            float s = 0.f;
#pragma unroll
            for (int q = 0; q < 16; ++q) {
                const float4 t = rp[q];
                s += t.x + t.y + t.z + t.w;
            }
            ksacc += s;
        }

        // ---- context outer product: 3x3 register tile per lane
#pragma unroll
        for (int q = 0; q < 16; ++q) {
            float4 e4[3], v4[3];
#pragma unroll
            for (int i = 0; i < 3; ++i)
                e4[i] = ((const float4*)(ek + (a + 8 * i) * PAD))[q];
#pragma unroll
            for (int j = 0; j < 3; ++j)
                v4[j] = ((const float4*)(vl + (b + 8 * j) * PAD))[q];
#pragma unroll
            for (int i = 0; i < 3; ++i)
#pragma unroll
                for (int j = 0; j < 3; ++j) {
                    float t = cacc[i * 3 + j];
                    t = fmaf(e4[i].x, v4[j].x, t);
                    t = fmaf(e4[i].y, v4[j].y, t);
                    t = fmaf(e4[i].z, v4[j].z, t);
                    t = fmaf(e4[i].w, v4[j].w, t);
                    cacc[i * 3 + j] = t;
                }
        }
    }

    // ---- one atomic flush per block
#pragma unroll
    for (int i = 0; i < 3; ++i)
#pragma unroll
        for (int j = 0; j < 3; ++j)
            atomicAdd(&ctx[((size_t)n * CC + gu * HK + a + 8 * i) * HK + b + 8 * j],
                      cacc[i * 3 + j]);
    if (pl < HK) atomicAdd(&ksum[n * CC + gu * HK + pl], ksacc);
}

// ---------------------------------------------------------------- kernel 2
// Mnt[n][kg][o]; one thread per output (72 blocks x 256 = 2*96*96 exactly)
__global__ __launch_bounds__(256) void k_combine(
    const float* __restrict__ Wr, const float* __restrict__ ctx,
    const float* __restrict__ ksum, float* __restrict__ Mnt)
{
    const int g  = blockIdx.x * 256 + threadIdx.x;
    const int n  = g / (CC * CC);
    const int r  = g % (CC * CC);
    const int kg = r / CC;
    const int o  = r % CC;
    const int h  = kg / HK;
    float a = 0.f;
#pragma unroll
    for (int v = 0; v < HK; ++v)
        a += Wr[o * CC + h * HK + v] * ctx[((size_t)n * CC + kg) * HK + v];
    Mnt[((size_t)n * CC + kg) * CC + o] = a / ksum[n * CC + kg];
}

// ---------------------------------------------------------------- kernel 3
// out[n][o][p] = sum_q Mnt[n][q][o] * qsm[n][q][p] + br[o]
// Wave w -> o in [24w, 24w+24); lane = position; 2 positions per lane.
// qsm float4 q-groups: element (n, q, p) at ((n*24+q/4)*NV+p)*4 + q%4.
__global__ __launch_bounds__(256) void k_out(
    const float* __restrict__ qsm, const float* __restrict__ Mnt,
    const float* __restrict__ br, float* __restrict__ out)
{
    const int tid = threadIdx.x;
    const int pl  = tid & 63;
    const int w   = __builtin_amdgcn_readfirstlane(tid >> 6);  // wave = o-group
    const int n   = blockIdx.x >> 10;          // grid = NB * (NV/128) = 2048
    const int pt  = blockIdx.x & 1023;
    const size_t p0 = (size_t)pt * 128 + pl;

    const float* __restrict__ Mb = Mnt + ((size_t)n * CC) * CC + w * HK;
    const float4* __restrict__ q4 = (const float4*)qsm + (size_t)n * 24 * NV + p0;

    float a0[HK], a1[HK];
#pragma unroll
    for (int j = 0; j < HK; ++j) { a0[j] = br[w * HK + j]; a1[j] = a0[j]; }

    auto FMAB = [&](int qg, const float4& v0, const float4& v1) {
        const float* __restrict__ m0 = Mb + (size_t)(4 * qg + 0) * CC;
        const float* __restrict__ m1 = Mb + (size_t)(4 * qg + 1) * CC;
        const float* __restrict__ m2 = Mb + (size_t)(4 * qg + 2) * CC;
        const float* __restrict__ m3 = Mb + (size_t)(4 * qg + 3) * CC;
#pragma unroll
        for (int j = 0; j < HK; ++j) {
            a0[j] = fmaf(m0[j], v0.x, a0[j]);
            a1[j] = fmaf(m0[j], v1.x, a1[j]);
        }
#pragma unroll
        for (int j = 0; j < HK; ++j) {
            a0[j] = fmaf(m1[j], v0.y, a0[j]);
            a1[j] = fmaf(m1[j], v1.y, a1[j]);
        }
#pragma unroll
        for (int j = 0; j < HK; ++j) {
            a0[j] = fmaf(m2[j], v0.z, a0[j]);
            a1[j] = fmaf(m2[j], v1.z, a1[j]);
        }
#pragma unroll
        for (int j = 0; j < HK; ++j) {
            a0[j] = fmaf(m3[j], v0.w, a0[j]);
            a1[j] = fmaf(m3[j], v1.w, a1[j]);
        }
    };

    float4 c0 = q4[0];
    float4 c1 = q4[64];
#pragma unroll 4
    for (int qg = 0; qg < 23; ++qg) {
        const float4 n0 = q4[(size_t)(qg + 1) * NV];
        const float4 n1 = q4[(size_t)(qg + 1) * NV + 64];
        FMAB(qg, c0, c1);
        c0 = n0; c1 = n1;
    }
    FMAB(23, c0, c1);

    float* __restrict__ ob = out + ((size_t)n * CC + (size_t)w * HK) * NV + p0;
#pragma unroll
    for (int j = 0; j < HK; ++j) {
        ob[(size_t)j * NV]      = a0[j];
        ob[(size_t)j * NV + 64] = a1[j];
    }
}

// ---------------------------------------------------------------- launch
extern "C" void kernel_launch(void* const* d_in, const int* in_sizes, int n_in,
                              void* d_out, int out_size, void* d_ws, size_t ws_size,
                              hipStream_t stream) {
    const float* x  = (const float*)d_in[0];
    const float* Wk = (const float*)d_in[1];
    const float* bk = (const float*)d_in[2];
    const float* Wq = (const float*)d_in[3];
    const float* bq = (const float*)d_in[4];
    const float* Wv = (const float*)d_in[5];
    const float* bv = (const float*)d_in[6];
    const float* Wr = (const float*)d_in[7];
    const float* br = (const float*)d_in[8];
    float* out = (float*)d_out;

    float* ws = (float*)d_ws;
    const size_t BIG = (size_t)NB * CC * NV;     // 25,165,824 floats
    float* qsm  = ws;                            // [2,24,NV,4] float4 q-groups
    float* ctx  = ws + BIG;                      // [2,96,24] = 4608
    float* ksum = ctx + (size_t)NB * CC * HK;    // [2,96]    = 192
    float* Mnt  = ksum + (size_t)NB * CC;        // [2,96,96] = 18432
    float* Wqt  = Mnt + (size_t)NB * CC * CC;    // [4,96,24] = 9216
    float* Wkt  = Wqt + CC * CC;
    float* Wvt  = Wkt + CC * CC;

    // zero atomic accumulators (ctx+ksum contiguous)
    hipMemsetAsync(ctx, 0, ((size_t)NB * CC * HK + (size_t)NB * CC) * sizeof(float), stream);

    k_prep<<<dim3((CC * CC + 255) / 256), dim3(256), 0, stream>>>(Wq, Wk, Wv, Wqt, Wkt, Wvt);
    k_fused<<<dim3(NB * BPN), dim3(256), 0, stream>>>(x, Wqt, bq, Wkt, bk, Wvt, bv, qsm, ctx, ksum);
    k_combine<<<dim3(NB * CC * CC / 256), dim3(256), 0, stream>>>(Wr, ctx, ksum, Mnt);
    k_out<<<dim3(NB * 1024), dim3(256), 0, stream>>>(qsm, Mnt, br, out);
}

// Round 5
// 554.417 us; speedup vs baseline: 1.6076x; 1.6076x over previous
//
#include <hip/hip_runtime.h>

// EfficientAttention MI355X — round 8:
//  * k_fused: VERBATIM revert to the round-5 body (measured 365 us; the two
//    restructures regressed: sweep-split 421 us, lambda ping-pong spilled to
//    scratch -> 721 us w/ 580 MB spill traffic). Plain qsm layout.
//  * k_out: M[n] (36 KB) staged in LDS once per block; per-q M row comes from
//    broadcast ds_read_b128 instead of K$-missing s_loads (M > 16 KB scalar L1
//    was forcing a ~200cyc lgkm stall per q-step). Same q order -> bit-identical.
//  * k_combine: parallel (72 blocks, thread per output).

#define NV 131072
#define CC 96
#define NB 2
#define HK 24
#define PAD 68
#define BPN 384          // k_fused blocks per batch index
#define TILES_N 2048     // 64-position tiles per batch index

// ---------------------------------------------------------------- kernel 0
__global__ __launch_bounds__(256) void k_prep(
    const float* __restrict__ Wq, const float* __restrict__ Wk,
    const float* __restrict__ Wv,
    float* __restrict__ Wqt, float* __restrict__ Wkt, float* __restrict__ Wvt)
{
    const int i = blockIdx.x * 256 + threadIdx.x;
    if (i >= CC * CC) return;
    const int h = i / (HK * CC);
    const int r = i % (HK * CC);
    const int c = r / HK;
    const int j = r % HK;
    const int src = (h * HK + j) * CC + c;
    Wqt[i] = Wq[src];
    Wkt[i] = Wk[src];
    Wvt[i] = Wv[src];
}

// ---------------------------------------------------------------- kernel 1
__global__ __launch_bounds__(256) void k_fused(
    const float* __restrict__ x,
    const float* __restrict__ Wqt, const float* __restrict__ bq,
    const float* __restrict__ Wkt, const float* __restrict__ bk,
    const float* __restrict__ Wvt, const float* __restrict__ bv,
    float* __restrict__ qsm, float* __restrict__ ctx, float* __restrict__ ksum)
{
    __shared__ float eks[4 * HK * PAD];   // per-wave exp(k) tiles [24][68]
    __shared__ float vls[4 * HK * PAD];   // per-wave v tiles      [24][68]
    const int tid = threadIdx.x;
    const int pl  = tid & 63;
    const int gu  = __builtin_amdgcn_readfirstlane(tid >> 6);  // wave = head
    const int n   = blockIdx.x / BPN;
    const int r0  = blockIdx.x % BPN;
    const int a   = pl >> 3, b = pl & 7;  // 8x8 lane grid for 3x3 ctx tile

    float* __restrict__ ek = eks + gu * HK * PAD;
    float* __restrict__ vl = vls + gu * HK * PAD;
    const float* __restrict__ Wqh = Wqt + gu * HK * CC;  // [c][j] contiguous
    const float* __restrict__ Wkh = Wkt + gu * HK * CC;
    const float* __restrict__ Wvh = Wvt + gu * HK * CC;

    float cacc[9];
#pragma unroll
    for (int k = 0; k < 9; ++k) cacc[k] = 0.f;
    float ksacc = 0.f;

    for (int tt = r0; tt < TILES_N; tt += BPN) {
        const size_t xb = (size_t)n * CC * NV + (size_t)tt * 64 + pl;

        // ---- projections: 72 simultaneous accumulators, x in 16-reg chunks
        float aq[HK], ak[HK], av[HK];
#pragma unroll
        for (int j = 0; j < HK; ++j) {
            aq[j] = bq[gu * HK + j];
            ak[j] = bk[gu * HK + j];
            av[j] = bv[gu * HK + j];
        }
        for (int ch = 0; ch < 6; ++ch) {
            float xr[16];
#pragma unroll
            for (int u = 0; u < 16; ++u)
                xr[u] = x[xb + (size_t)(ch * 16 + u) * NV];
#pragma unroll
            for (int u = 0; u < 16; ++u) {
                const int c = ch * 16 + u;
#pragma unroll
                for (int j = 0; j < HK; ++j) {
                    aq[j] = fmaf(Wqh[c * HK + j], xr[u], aq[j]);
                    ak[j] = fmaf(Wkh[c * HK + j], xr[u], ak[j]);
                    av[j] = fmaf(Wvh[c * HK + j], xr[u], av[j]);
                }
            }
        }

        // ---- q softmax (registers) -> qsm
        {
            float mx = aq[0];
#pragma unroll
            for (int j = 1; j < HK; ++j) mx = fmaxf(mx, aq[j]);
            float s = 0.f;
#pragma unroll
            for (int j = 0; j < HK; ++j) { aq[j] = __expf(aq[j] - mx); s += aq[j]; }
            const float inv = 1.f / s;
            const size_t qb = ((size_t)n * CC + gu * HK) * NV + (size_t)tt * 64 + pl;
#pragma unroll
            for (int j = 0; j < HK; ++j)
                qsm[qb + (size_t)j * NV] = aq[j] * inv;
        }

        // ---- exp(k) and v into this wave's private LDS (no barrier needed)
#pragma unroll
        for (int j = 0; j < HK; ++j) ek[j * PAD + pl] = __expf(ak[j]);
#pragma unroll
        for (int j = 0; j < HK; ++j) vl[j * PAD + pl] = av[j];

        // ---- ksum: lane < 24 sums its exp(k) row
        if (pl < HK) {
            const float4* __restrict__ rp = (const float4*)(ek + pl * PAD);
            float s = 0.f;
#pragma unroll
            for (int q = 0; q < 16; ++q) {
                const float4 t = rp[q];
                s += t.x + t.y + t.z + t.w;
            }
            ksacc += s;
        }

        // ---- context outer product: 3x3 register tile per lane
#pragma unroll
        for (int q = 0; q < 16; ++q) {
            float4 e4[3], v4[3];
#pragma unroll
            for (int i = 0; i < 3; ++i)
                e4[i] = ((const float4*)(ek + (a + 8 * i) * PAD))[q];
#pragma unroll
            for (int j = 0; j < 3; ++j)
                v4[j] = ((const float4*)(vl + (b + 8 * j) * PAD))[q];
#pragma unroll
            for (int i = 0; i < 3; ++i)
#pragma unroll
                for (int j = 0; j < 3; ++j) {
                    float t = cacc[i * 3 + j];
                    t = fmaf(e4[i].x, v4[j].x, t);
                    t = fmaf(e4[i].y, v4[j].y, t);
                    t = fmaf(e4[i].z, v4[j].z, t);
                    t = fmaf(e4[i].w, v4[j].w, t);
                    cacc[i * 3 + j] = t;
                }
        }
    }

    // ---- one atomic flush per block
#pragma unroll
    for (int i = 0; i < 3; ++i)
#pragma unroll
        for (int j = 0; j < 3; ++j)
            atomicAdd(&ctx[((size_t)n * CC + gu * HK + a + 8 * i) * HK + b + 8 * j],
                      cacc[i * 3 + j]);
    if (pl < HK) atomicAdd(&ksum[n * CC + gu * HK + pl], ksacc);
}

// ---------------------------------------------------------------- kernel 2
// Mnt[n][kg][o]; one thread per output (72 blocks x 256 = 2*96*96 exactly)
__global__ __launch_bounds__(256) void k_combine(
    const float* __restrict__ Wr, const float* __restrict__ ctx,
    const float* __restrict__ ksum, float* __restrict__ Mnt)
{
    const int g  = blockIdx.x * 256 + threadIdx.x;
    const int n  = g / (CC * CC);
    const int r  = g % (CC * CC);
    const int kg = r / CC;
    const int o  = r % CC;
    const int h  = kg / HK;
    float a = 0.f;
#pragma unroll
    for (int v = 0; v < HK; ++v)
        a += Wr[o * CC + h * HK + v] * ctx[((size_t)n * CC + kg) * HK + v];
    Mnt[((size_t)n * CC + kg) * CC + o] = a / ksum[n * CC + kg];
}

// ---------------------------------------------------------------- kernel 3
// out[n][o][p] = sum_q Mnt[n][q][o] * qsm[n][q][p] + br[o]
// Wave w -> o in [24w, 24w+24); lane = position; 2 positions per lane.
// M[n] (96x96 = 36 KB) staged in LDS once per block; per-q row slice is a
// broadcast (wave-uniform) ds_read_b128 x6 — no scalar-cache misses.
__global__ __launch_bounds__(256) void k_out(
    const float* __restrict__ qsm, const float* __restrict__ Mnt,
    const float* __restrict__ br, float* __restrict__ out)
{
    __shared__ float lm[CC * CC];              // 36864 B -> 4 blocks/CU
    const int tid = threadIdx.x;
    const int pl  = tid & 63;
    const int w   = __builtin_amdgcn_readfirstlane(tid >> 6);  // wave = o-group
    const int n   = blockIdx.x >> 10;          // grid = NB * (NV/128) = 2048
    const int pt  = blockIdx.x & 1023;
    const size_t p0 = (size_t)pt * 128 + pl;

    // stage M[n] into LDS (coalesced float4, 9 per thread)
    {
        const float4* __restrict__ Ms = (const float4*)(Mnt + (size_t)n * CC * CC);
        float4* __restrict__ ld4 = (float4*)lm;
#pragma unroll
        for (int i = 0; i < 9; ++i)
            ld4[tid + 256 * i] = Ms[tid + 256 * i];
    }
    __syncthreads();

    const float* __restrict__ mbase = lm + w * HK;   // this wave's 24-col slice
    const float* __restrict__ qb = qsm + (size_t)n * CC * NV + p0;

    float a0[HK], a1[HK];
#pragma unroll
    for (int j = 0; j < HK; ++j) { a0[j] = br[w * HK + j]; a1[j] = a0[j]; }

#pragma unroll 4
    for (int q = 0; q < CC; ++q) {
        const float q0 = qb[(size_t)q * NV];
        const float q1 = qb[(size_t)q * NV + 64];
        const float4* __restrict__ m4 = (const float4*)(mbase + q * CC);  // 16B-aligned
        float4 mv[6];
#pragma unroll
        for (int t = 0; t < 6; ++t) mv[t] = m4[t];
#pragma unroll
        for (int t = 0; t < 6; ++t) {
            a0[4 * t + 0] = fmaf(mv[t].x, q0, a0[4 * t + 0]);
            a0[4 * t + 1] = fmaf(mv[t].y, q0, a0[4 * t + 1]);
            a0[4 * t + 2] = fmaf(mv[t].z, q0, a0[4 * t + 2]);
            a0[4 * t + 3] = fmaf(mv[t].w, q0, a0[4 * t + 3]);
            a1[4 * t + 0] = fmaf(mv[t].x, q1, a1[4 * t + 0]);
            a1[4 * t + 1] = fmaf(mv[t].y, q1, a1[4 * t + 1]);
            a1[4 * t + 2] = fmaf(mv[t].z, q1, a1[4 * t + 2]);
            a1[4 * t + 3] = fmaf(mv[t].w, q1, a1[4 * t + 3]);
        }
    }

    float* __restrict__ ob = out + ((size_t)n * CC + (size_t)w * HK) * NV + p0;
#pragma unroll
    for (int j = 0; j < HK; ++j) {
        ob[(size_t)j * NV]      = a0[j];
        ob[(size_t)j * NV + 64] = a1[j];
    }
}

// ---------------------------------------------------------------- launch
extern "C" void kernel_launch(void* const* d_in, const int* in_sizes, int n_in,
                              void* d_out, int out_size, void* d_ws, size_t ws_size,
                              hipStream_t stream) {
    const float* x  = (const float*)d_in[0];
    const float* Wk = (const float*)d_in[1];
    const float* bk = (const float*)d_in[2];
    const float* Wq = (const float*)d_in[3];
    const float* bq = (const float*)d_in[4];
    const float* Wv = (const float*)d_in[5];
    const float* bv = (const float*)d_in[6];
    const float* Wr = (const float*)d_in[7];
    const float* br = (const float*)d_in[8];
    float* out = (float*)d_out;

    float* ws = (float*)d_ws;
    const size_t BIG = (size_t)NB * CC * NV;     // 25,165,824 floats
    float* qsm  = ws;                            // [2,96,NV]
    float* ctx  = ws + BIG;                      // [2,96,24] = 4608
    float* ksum = ctx + (size_t)NB * CC * HK;    // [2,96]    = 192
    float* Mnt  = ksum + (size_t)NB * CC;        // [2,96,96] = 18432
    float* Wqt  = Mnt + (size_t)NB * CC * CC;    // [4,96,24] = 9216
    float* Wkt  = Wqt + CC * CC;
    float* Wvt  = Wkt + CC * CC;

    // zero atomic accumulators (ctx+ksum contiguous)
    hipMemsetAsync(ctx, 0, ((size_t)NB * CC * HK + (size_t)NB * CC) * sizeof(float), stream);

    k_prep<<<dim3((CC * CC + 255) / 256), dim3(256), 0, stream>>>(Wq, Wk, Wv, Wqt, Wkt, Wvt);
    k_fused<<<dim3(NB * BPN), dim3(256), 0, stream>>>(x, Wqt, bq, Wkt, bk, Wvt, bv, qsm, ctx, ksum);
    k_combine<<<dim3(NB * CC * CC / 256), dim3(256), 0, stream>>>(Wr, ctx, ksum, Mnt);
    k_out<<<dim3(NB * 1024), dim3(256), 0, stream>>>(qsm, Mnt, br, out);
}